// Round 20
// baseline (272.022 us; speedup 1.0000x reference)
//
#include <hip/hip_runtime.h>
#include <hip/hip_bf16.h>
#include <stdint.h>

typedef __attribute__((ext_vector_type(8))) __bf16 bf16x8;
typedef __attribute__((ext_vector_type(4))) __bf16 bf16x4;
typedef __attribute__((ext_vector_type(4))) float f32x4;

#define DEV __device__ __forceinline__

static constexpr int S = 2048, F = 2048, H = 16, D = 128;
static constexpr int KDIM = F;            // 2048
static constexpr float QSCALE = 0.08838834764831845f;  // 1/sqrt(128)

DEV void gll16(const void* g, void* l) {
  __builtin_amdgcn_global_load_lds(
      (const __attribute__((address_space(1))) void*)g,
      (__attribute__((address_space(3))) void*)l, 16, 0, 0);
}

DEV f32x4 mfma16(bf16x8 a, bf16x8 b, f32x4 c) {
  return __builtin_amdgcn_mfma_f32_16x16x32_bf16(a, b, c, 0, 0, 0);
}

extern __shared__ char smem[];

#define QBAR()  __builtin_amdgcn_s_barrier()
#define QLGKM() asm volatile("s_waitcnt lgkmcnt(0)" ::: "memory")
#define QSCB()  __builtin_amdgcn_sched_barrier(0)

// ---------------- fused prep: x->bf16 cvt + both weight transposes ----------------
__global__ void k_prep(const float* __restrict__ x, __bf16* __restrict__ xb,
                       const float* __restrict__ wa, __bf16* __restrict__ wat,
                       const float* __restrict__ wp, __bf16* __restrict__ wpt) {
  __shared__ float t[64][65];
  const int bid = blockIdx.x;
  if (bid < 8192) {
    int i = bid * 256 + threadIdx.x;
    float4 v = reinterpret_cast<const float4*>(x)[i];
    bf16x4 o = {(__bf16)v.x, (__bf16)v.y, (__bf16)v.z, (__bf16)v.w};
    reinterpret_cast<bf16x4*>(xb)[i] = o;
    return;
  }
  const float* in;
  __bf16* out;
  int rows, cols, c0, r0;
  if (bid < 11264) {
    int tb = bid - 8192;
    in = wa; out = wat; rows = 2048; cols = 6144;
    c0 = (tb % 96) * 64; r0 = (tb / 96) * 64;
  } else {
    int tb = bid - 11264;
    in = wp; out = wpt; rows = 2048; cols = 2048;
    c0 = (tb % 32) * 64; r0 = (tb / 32) * 64;
  }
  const int tx = threadIdx.x & 63, ty = threadIdx.x >> 6;
#pragma unroll
  for (int i = 0; i < 64; i += 4)
    t[ty + i][tx] = in[(size_t)(r0 + ty + i) * cols + c0 + tx];
  __syncthreads();
#pragma unroll
  for (int i = 0; i < 64; i += 4)
    out[(size_t)(c0 + ty + i) * rows + r0 + tx] = (__bf16)t[tx][ty + i];
}

// ================= QKV: 8-phase barrier-dense GEMM, 128x384 tile, BK=64 ==========
// (r17 — measured 105.3 us, MfmaUtil 42%, no spill, tail-free 512 blocks)
__global__ __launch_bounds__(512, 1) void k_qkv8p(
    const __bf16* __restrict__ A, const __bf16* __restrict__ Bt,
    const float* __restrict__ bias,
    __bf16* __restrict__ qo, __bf16* __restrict__ ko, __bf16* __restrict__ vo) {
  constexpr int NT = 32;
  const int tid = threadIdx.x;
  const int lane = tid & 63, wid = tid >> 6;
  const int wm = wid >> 2, wn = wid & 3;
  const int ln = lane & 15, lm = lane >> 4;

  const int lin = (blockIdx.x & 7) * 64 + (blockIdx.x >> 3);
  const int by = lin >> 4, bx = lin & 15;
  const int mBase = by * 128, nBase = bx * 384;

  const int r0 = tid >> 3, cc = tid & 7;
  const int src0 = r0 * KDIM + ((cc ^ (r0 & 7)) << 3);
  const __bf16* Ab = A + (size_t)mBase * KDIM + src0;
  const __bf16* Bb = Bt + (size_t)nBase * KDIM + src0;
  const int sDst = wid * 1024;

  auto stA2 = [&](int t) {
    char* d = smem + (t & 1) * 65536 + sDst;
    const __bf16* s = Ab + t * 64;
    gll16(s, d);
    gll16(s + (size_t)64 * KDIM, d + 8192);
  };
  auto stB2 = [&](int t, int j) {
    char* d = smem + (t & 1) * 65536 + 16384 + j * 8192 + sDst;
    const __bf16* s = Bb + (size_t)j * 64 * KDIM + t * 64;
    gll16(s, d);
    gll16(s + (size_t)64 * KDIM, d + 8192);
  };

  int rA[2], rB[2];
#pragma unroll
  for (int ks = 0; ks < 2; ++ks) {
    const int slot = (ks * 4 + lm) ^ (ln & 7);
    rA[ks] = (wm * 64 + ln) * 128 + slot * 16;
    rB[ks] = 16384 + (wn * 96 + ln) * 128 + slot * 16;
  }
  auto rdA = [&](bf16x8 (&a)[4], const char* cb, int ks) {
#pragma unroll
    for (int mi = 0; mi < 4; ++mi)
      a[mi] = *reinterpret_cast<const bf16x8*>(cb + rA[ks] + mi * 2048);
  };
  auto rdBh = [&](bf16x8 (&b)[3], const char* cb, int ks, int h) {
#pragma unroll
    for (int k = 0; k < 3; ++k)
      b[k] = *reinterpret_cast<const bf16x8*>(cb + rB[ks] + (h * 3 + k) * 2048);
  };

  f32x4 acc[4][6] = {};
  auto mm = [&](const bf16x8 (&a)[4], const bf16x8 (&b)[3], int h) {
#pragma unroll
    for (int k = 0; k < 3; ++k)
#pragma unroll
      for (int mi = 0; mi < 4; ++mi)
        acc[mi][h * 3 + k] = mfma16(a[mi], b[k], acc[mi][h * 3 + k]);
  };

  stA2(0); stB2(0, 0); stB2(0, 2); stB2(0, 4); stA2(1);
  asm volatile("s_waitcnt vmcnt(2)" ::: "memory");
  QBAR(); QSCB();

  for (int i = 0; i < 16; ++i) {
    const char* L = smem;
    const char* R = smem + 65536;
    const int tR = 2 * i + 1, tN = 2 * i + 2, tN1 = 2 * i + 3;
    const bool last = (i == 15);
    bf16x8 a[4], b[3];

    rdA(a, L, 0); rdBh(b, L, 0, 0);
    stB2(tR, 0);
    QBAR(); QLGKM(); QSCB();
    __builtin_amdgcn_s_setprio(1); mm(a, b, 0); __builtin_amdgcn_s_setprio(0);
    QBAR(); QSCB();

    rdBh(b, L, 0, 1);
    stB2(tR, 2);
    QBAR(); QLGKM(); QSCB();
    __builtin_amdgcn_s_setprio(1); mm(a, b, 1); __builtin_amdgcn_s_setprio(0);
    QBAR(); QSCB();

    rdA(a, L, 1); rdBh(b, L, 1, 1);
    stB2(tR, 4);
    QBAR(); QLGKM(); QSCB();
    __builtin_amdgcn_s_setprio(1); mm(a, b, 1); __builtin_amdgcn_s_setprio(0);
    QBAR(); QSCB();

    rdBh(b, L, 1, 0);
    if (!last) stA2(tN);
    QBAR(); QLGKM(); QSCB();
    __builtin_amdgcn_s_setprio(1); mm(a, b, 0); __builtin_amdgcn_s_setprio(0);
    if (last) asm volatile("s_waitcnt vmcnt(0)" ::: "memory");
    else      asm volatile("s_waitcnt vmcnt(2)" ::: "memory");
    QBAR(); QSCB();

    rdA(a, R, 0); rdBh(b, R, 0, 0);
    if (!last) stB2(tN, 0);
    QBAR(); QLGKM(); QSCB();
    __builtin_amdgcn_s_setprio(1); mm(a, b, 0); __builtin_amdgcn_s_setprio(0);
    QBAR(); QSCB();

    rdBh(b, R, 0, 1);
    if (!last) stB2(tN, 2);
    QBAR(); QLGKM(); QSCB();
    __builtin_amdgcn_s_setprio(1); mm(a, b, 1); __builtin_amdgcn_s_setprio(0);
    QBAR(); QSCB();

    rdA(a, R, 1); rdBh(b, R, 1, 1);
    if (!last) stB2(tN, 4);
    QBAR(); QLGKM(); QSCB();
    __builtin_amdgcn_s_setprio(1); mm(a, b, 1); __builtin_amdgcn_s_setprio(0);
    QBAR(); QSCB();

    rdBh(b, R, 1, 0);
    if (tN1 < NT) stA2(tN1);
    QBAR(); QLGKM(); QSCB();
    __builtin_amdgcn_s_setprio(1); mm(a, b, 0); __builtin_amdgcn_s_setprio(0);
    if (!last) {
      asm volatile("s_waitcnt vmcnt(2)" ::: "memory");
      QBAR(); QSCB();
    }
  }

#pragma unroll
  for (int mi = 0; mi < 4; ++mi) {
    const int grow = mBase + wm * 64 + mi * 16 + lm * 4;
    const int b = grow >> 11, s0 = grow & 2047;
#pragma unroll
    for (int ni = 0; ni < 6; ++ni) {
      const int gcol = nBase + wn * 96 + ni * 16 + ln;
      const float bv = bias[gcol];
      const int sec = gcol >> 11;
      const int h = (gcol >> 7) & 15, d = gcol & 127;
      const int bh = b * H + h;
      if (sec == 0) {
#pragma unroll
        for (int r = 0; r < 4; ++r)
          qo[((size_t)bh * S + s0 + r) * D + d] = (__bf16)((acc[mi][ni][r] + bv) * QSCALE);
      } else if (sec == 1) {
#pragma unroll
        for (int r = 0; r < 4; ++r)
          ko[((size_t)bh * S + s0 + r) * D + d] = (__bf16)(acc[mi][ni][r] + bv);
      } else {
        bf16x4 pv = {(__bf16)(acc[mi][ni][0] + bv), (__bf16)(acc[mi][ni][1] + bv),
                     (__bf16)(acc[mi][ni][2] + bv), (__bf16)(acc[mi][ni][3] + bv)};
        *reinterpret_cast<bf16x4*>(vo + ((size_t)bh * D + d) * S + s0) = pv;  // V^T
      }
    }
  }
}

// ================= out-proj: 8-phase barrier-dense GEMM, 128x256 tile =============
// (r18 — best proj)
__global__ __launch_bounds__(512, 1) void k_proj8p(
    const __bf16* __restrict__ A, const __bf16* __restrict__ Bt,
    const float* __restrict__ bias, float* __restrict__ fo) {
  constexpr int NT = 32;
  const int tid = threadIdx.x;
  const int lane = tid & 63, wid = tid >> 6;
  const int wm = wid >> 2, wn = wid & 3;
  const int ln = lane & 15, lm = lane >> 4;

  const int lin = (blockIdx.x & 7) * 32 + (blockIdx.x >> 3);
  const int by = lin >> 3, bx = lin & 7;
  const int mBase = by * 128, nBase = bx * 256;

  const int r0 = tid >> 3, cc = tid & 7;
  const int src0 = r0 * KDIM + ((cc ^ (r0 & 7)) << 3);
  const __bf16* Ab = A + (size_t)mBase * KDIM + src0;
  const __bf16* Bb = Bt + (size_t)nBase * KDIM + src0;
  const int sDst = wid * 1024;

  auto stA2 = [&](int t) {
    char* d = smem + (t & 1) * 49152 + sDst;
    const __bf16* s = Ab + t * 64;
    gll16(s, d);
    gll16(s + (size_t)64 * KDIM, d + 8192);
  };
  auto stB2 = [&](int t, int j) {
    char* d = smem + (t & 1) * 49152 + 16384 + j * 8192 + sDst;
    const __bf16* s = Bb + (size_t)j * 64 * KDIM + t * 64;
    gll16(s, d);
    gll16(s + (size_t)64 * KDIM, d + 8192);
  };

  int rA[2], rB[2];
#pragma unroll
  for (int ks = 0; ks < 2; ++ks) {
    const int slot = (ks * 4 + lm) ^ (ln & 7);
    rA[ks] = (wm * 64 + ln) * 128 + slot * 16;
    rB[ks] = 16384 + (wn * 64 + ln) * 128 + slot * 16;
  }
  auto rdA = [&](bf16x8 (&a)[4], const char* cb, int ks) {
#pragma unroll
    for (int mi = 0; mi < 4; ++mi)
      a[mi] = *reinterpret_cast<const bf16x8*>(cb + rA[ks] + mi * 2048);
  };
  auto rdBh = [&](bf16x8 (&b)[2], const char* cb, int ks, int h) {
#pragma unroll
    for (int k = 0; k < 2; ++k)
      b[k] = *reinterpret_cast<const bf16x8*>(cb + rB[ks] + (h * 2 + k) * 2048);
  };

  f32x4 acc[4][4] = {};
  auto mm = [&](const bf16x8 (&a)[4], const bf16x8 (&b)[2], int h) {
#pragma unroll
    for (int k = 0; k < 2; ++k)
#pragma unroll
      for (int mi = 0; mi < 4; ++mi)
        acc[mi][h * 2 + k] = mfma16(a[mi], b[k], acc[mi][h * 2 + k]);
  };

  stA2(0); stB2(0, 0); stB2(0, 2); stA2(1);
  asm volatile("s_waitcnt vmcnt(2)" ::: "memory");
  QBAR(); QSCB();

  for (int i = 0; i < 16; ++i) {
    const char* L = smem;
    const char* R = smem + 49152;
    const int tR = 2 * i + 1, tN = 2 * i + 2, tN1 = 2 * i + 3;
    const bool last = (i == 15);
    bf16x8 a[4], b[2];

    rdA(a, L, 0); rdBh(b, L, 0, 0);
    stB2(tR, 0);
    QBAR(); QLGKM(); QSCB();
    __builtin_amdgcn_s_setprio(1); mm(a, b, 0); __builtin_amdgcn_s_setprio(0);
    QBAR(); QSCB();

    rdBh(b, L, 0, 1);
    stB2(tR, 2);
    QBAR(); QLGKM(); QSCB();
    __builtin_amdgcn_s_setprio(1); mm(a, b, 1); __builtin_amdgcn_s_setprio(0);
    QBAR(); QSCB();

    rdA(a, L, 1); rdBh(b, L, 1, 1);
    if (!last) stA2(tN);
    QBAR(); QLGKM(); QSCB();
    __builtin_amdgcn_s_setprio(1); mm(a, b, 1); __builtin_amdgcn_s_setprio(0);
    QBAR(); QSCB();

    rdBh(b, L, 1, 0);
    QBAR(); QLGKM(); QSCB();
    __builtin_amdgcn_s_setprio(1); mm(a, b, 0); __builtin_amdgcn_s_setprio(0);
    if (last) asm volatile("s_waitcnt vmcnt(0)" ::: "memory");
    else      asm volatile("s_waitcnt vmcnt(2)" ::: "memory");
    QBAR(); QSCB();

    rdA(a, R, 0); rdBh(b, R, 0, 0);
    if (!last) stB2(tN, 0);
    QBAR(); QLGKM(); QSCB();
    __builtin_amdgcn_s_setprio(1); mm(a, b, 0); __builtin_amdgcn_s_setprio(0);
    QBAR(); QSCB();

    rdBh(b, R, 0, 1);
    if (!last) stB2(tN, 2);
    QBAR(); QLGKM(); QSCB();
    __builtin_amdgcn_s_setprio(1); mm(a, b, 1); __builtin_amdgcn_s_setprio(0);
    QBAR(); QSCB();

    rdA(a, R, 1); rdBh(b, R, 1, 1);
    if (tN1 < NT) stA2(tN1);
    QBAR(); QLGKM(); QSCB();
    __builtin_amdgcn_s_setprio(1); mm(a, b, 1); __builtin_amdgcn_s_setprio(0);
    QBAR(); QSCB();

    rdBh(b, R, 1, 0);
    QBAR(); QLGKM(); QSCB();
    __builtin_amdgcn_s_setprio(1); mm(a, b, 0); __builtin_amdgcn_s_setprio(0);
    if (!last) {
      asm volatile("s_waitcnt vmcnt(2)" ::: "memory");
      QBAR(); QSCB();
    }
  }

#pragma unroll
  for (int mi = 0; mi < 4; ++mi) {
    const int grow = mBase + wm * 64 + mi * 16 + lm * 4;
#pragma unroll
    for (int ni = 0; ni < 4; ++ni) {
      const int gcol = nBase + wn * 64 + ni * 16 + ln;
      const float bv = bias[gcol];
#pragma unroll
      for (int r = 0; r < 4; ++r)
        fo[(size_t)(grow + r) * F + gcol] = acc[mi][ni][r] + bv;
    }
  }
}

// ---------------- flash attention: swapped-operand + NO V-STAGING (R20) ----------
// V for a bh is L2-resident (512 KB << 4 MB; all 16 q-blocks of a bh share one
// XCD: blk&7 = (bh>>1)&7). PV reads V^T A-frags DIRECTLY from global (16 B
// contiguous per lane; 4-lane lm-groups cover 64 B). Drops per tile: 4 DMA
// loads, 16 ds_read_b128/wave; LDS 80->48 KB (K dbuf 2x16K + P 16K) -> 3
// blocks/CU fit -> all 512 blocks co-resident (no 2nd-round imbalance).
// Ledger: stage = 4 K-loads; prologue vmcnt(4) => tile0 landed; boundary
// vmcnt(4) => kt+1 landed (V loads retired by compiler waits before PV MFMAs).
__global__ __launch_bounds__(256, 2) void k_attn(
    const __bf16* __restrict__ qb, const __bf16* __restrict__ kb,
    const __bf16* __restrict__ vtb, __bf16* __restrict__ zb) {
  const int lane = threadIdx.x & 63, w = threadIdx.x >> 6;
  const int lm = lane >> 4, ln = lane & 15;
  const int blk = blockIdx.x;
  const int u = blk & 255, v = blk >> 8;
  const int qt = v ? (u >> 4) : 15 - (u >> 4);
  const int bh = ((u & 15) << 1) | v;
  const int qw = qt * 128 + w * 32;

  const __bf16* qp = qb + (size_t)bh * S * D;
  const __bf16* kp = kb + (size_t)bh * S * D;
  const __bf16* vp = vtb + (size_t)bh * D * S;
  char* pw = smem + 32768 + w * 4096;

  int ksrc[4], kdst[4];
#pragma unroll
  for (int j = 0; j < 4; ++j) {
    int c = (w * 4 + j) * 64 + lane;
    int kr = c >> 4, kps = (c & 15) ^ (kr & 7);
    ksrc[j] = kr * D + kps * 8;
    kdst[j] = (w * 4 + j) * 1024;
  }
  auto stage = [&](int kt) {  // K only: 4 loads into buf (kt&1)
    char* buf = smem + (kt & 1) * 16384;
    const int kv = kt * 64;
#pragma unroll
    for (int j = 0; j < 4; ++j) gll16(kp + (size_t)kv * D + ksrc[j], buf + kdst[j]);
  };

  // Q frags (B-operand): col=q=qw+nj*16+ln, k-elems d=kf*32+lm*8..
  bf16x8 qf[2][4];
#pragma unroll
  for (int nj = 0; nj < 2; ++nj)
#pragma unroll
    for (int kf = 0; kf < 4; ++kf)
      qf[nj][kf] = *reinterpret_cast<const bf16x8*>(qp + (qw + nj * 16 + ln) * D + kf * 32 + lm * 8);

  f32x4 Oa[8][2] = {};            // O^T: [d-frag][q-frag]
  float mrow[2], lrow[2];
#pragma unroll
  for (int nj = 0; nj < 2; ++nj) { mrow[nj] = -3.0e38f; lrow[nj] = 0.0f; }

  const int ktEnd = 2 * qt + 1;

  stage(0);
  stage(1);
  asm volatile("s_waitcnt vmcnt(4)" ::: "memory");  // tile 0 landed
  QBAR(); QSCB();

  for (int kt = 0; kt <= ktEnd; ++kt) {
    const int kv0 = kt * 64;
    const char* Kb = smem + (kt & 1) * 16384;

    if (kv0 <= qw + 31) {
      const bool diag = (kv0 + 63 > qw);

      // S^T = K Q^T : M=64(kv) N=32(q) K=128(d)
      f32x4 sacc[4][2] = {};
#pragma unroll
      for (int kf = 0; kf < 4; ++kf) {
        bf16x8 kfr[4];  // A: row=kv=mi*16+ln, k=d=kf*32+lm*8..
#pragma unroll
        for (int mi = 0; mi < 4; ++mi) {
          int row = mi * 16 + ln;
          int ch = (kf * 4 + lm) ^ (row & 7);
          kfr[mi] = *reinterpret_cast<const bf16x8*>(Kb + row * 256 + ch * 16);
        }
        __builtin_amdgcn_s_setprio(1);
#pragma unroll
        for (int mi = 0; mi < 4; ++mi)
#pragma unroll
          for (int nj = 0; nj < 2; ++nj)
            sacc[mi][nj] = mfma16(kfr[mi], qf[nj][kf], sacc[mi][nj]);
        __builtin_amdgcn_s_setprio(0);
      }

      if (diag) {
#pragma unroll
        for (int nj = 0; nj < 2; ++nj) {
          int q = qw + nj * 16 + ln;
#pragma unroll
          for (int mi = 0; mi < 4; ++mi) {
            int kvb = kv0 + mi * 16 + lm * 4;
#pragma unroll
            for (int r = 0; r < 4; ++r)
              if (kvb + r > q) sacc[mi][nj][r] = -1e30f;
          }
        }
      }

      // softmax: lane owns 16 kv of its q-row; lane-partial fast-path trigger
      float lmax[2];
      bool big = false;
#pragma unroll
      for (int nj = 0; nj < 2; ++nj) {
        float m4 = -3.0e38f;
#pragma unroll
        for (int mi = 0; mi < 4; ++mi)
#pragma unroll
          for (int r = 0; r < 4; ++r) m4 = fmaxf(m4, sacc[mi][nj][r]);
        lmax[nj] = m4;
        big = big || (m4 > mrow[nj] + 8.0f);
      }
      if (__any((int)big)) {  // rare: 2-shuffle row reduce + rescale
#pragma unroll
        for (int nj = 0; nj < 2; ++nj) {
          float mx = lmax[nj];
          mx = fmaxf(mx, __shfl_xor(mx, 16, 64));
          mx = fmaxf(mx, __shfl_xor(mx, 32, 64));
          float mnew = fmaxf(mrow[nj], mx);
          float corr = __expf(mrow[nj] - mnew);
          mrow[nj] = mnew;
          lrow[nj] *= corr;
#pragma unroll
          for (int ni = 0; ni < 8; ++ni)
#pragma unroll
            for (int r = 0; r < 4; ++r) Oa[ni][nj][r] *= corr;
        }
      }
#pragma unroll
      for (int nj = 0; nj < 2; ++nj) {
        float rs = 0.0f;
#pragma unroll
        for (int mi = 0; mi < 4; ++mi)
#pragma unroll
          for (int r = 0; r < 4; ++r) {
            float p = __expf(sacc[mi][nj][r] - mrow[nj]);  // bounded by e^8
            sacc[mi][nj][r] = p;
            rs += p;
          }
        lrow[nj] += rs;
      }

      // P^T -> per-wave LDS: 8 b64 writes (row q=nj*16+ln, XOR-swz)
#pragma unroll
      for (int nj = 0; nj < 2; ++nj) {
        int row = nj * 16 + ln;
        int rb = row * 128;
        int swz = (row & 7) << 4;
#pragma unroll
        for (int mi = 0; mi < 4; ++mi) {
          bf16x4 pq = {(__bf16)sacc[mi][nj][0], (__bf16)sacc[mi][nj][1],
                       (__bf16)sacc[mi][nj][2], (__bf16)sacc[mi][nj][3]};
          *reinterpret_cast<bf16x4*>(pw + rb + ((mi * 32 + lm * 8) ^ swz)) = pq;
        }
      }

      QLGKM(); QSCB();

      // O^T += V^T P^T : M=128(d) N=32(q) K=64(kv); V^T read direct from global
#pragma unroll
      for (int kf = 0; kf < 2; ++kf) {
        bf16x8 pfr[2], vfr[8];
#pragma unroll
        for (int nj = 0; nj < 2; ++nj) {
          int row = nj * 16 + ln;
          pfr[nj] = *reinterpret_cast<const bf16x8*>(
              pw + row * 128 + ((kf * 64 + lm * 16) ^ ((row & 7) << 4)));
        }
#pragma unroll
        for (int ni = 0; ni < 8; ++ni) {  // A: row=d=ni*16+ln, k=kv (L2-resident)
          vfr[ni] = *reinterpret_cast<const bf16x8*>(
              vp + (size_t)(ni * 16 + ln) * S + kv0 + kf * 32 + lm * 8);
        }
        __builtin_amdgcn_s_setprio(1);
#pragma unroll
        for (int ni = 0; ni < 8; ++ni)
#pragma unroll
          for (int nj = 0; nj < 2; ++nj)
            Oa[ni][nj] = mfma16(vfr[ni], pfr[nj], Oa[ni][nj]);
        __builtin_amdgcn_s_setprio(0);
      }
    }

    // ---- tile boundary: counted waits, never drain mid-loop ----
    asm volatile("s_waitcnt lgkmcnt(0)" ::: "memory");
    QBAR(); QSCB();
    if (kt + 2 <= ktEnd) stage(kt + 2);
    if (kt + 1 <= ktEnd) {
      if (kt + 2 <= ktEnd)
        asm volatile("s_waitcnt vmcnt(4)" ::: "memory");  // kt+1 landed
      else
        asm volatile("s_waitcnt vmcnt(0)" ::: "memory");
      QBAR(); QSCB();
    }
  }

  // finish: 2-shuffle row-sum reduce, normalize, packed 8B stores
#pragma unroll
  for (int nj = 0; nj < 2; ++nj) {
    float ls = lrow[nj];
    ls += __shfl_xor(ls, 16, 64);
    ls += __shfl_xor(ls, 32, 64);
    lrow[nj] = 1.0f / ls;
  }
  const int b = bh >> 4, h = bh & 15;
#pragma unroll
  for (int nj = 0; nj < 2; ++nj) {
    const int qrow = qw + nj * 16 + ln;
    __bf16* zrow = zb + (size_t)(b * S + qrow) * F + h * D + lm * 4;
#pragma unroll
    for (int ni = 0; ni < 8; ++ni) {
      bf16x4 oq = {(__bf16)(Oa[ni][nj][0] * lrow[nj]), (__bf16)(Oa[ni][nj][1] * lrow[nj]),
                   (__bf16)(Oa[ni][nj][2] * lrow[nj]), (__bf16)(Oa[ni][nj][3] * lrow[nj])};
      *reinterpret_cast<bf16x4*>(zrow + ni * 16) = oq;
    }
  }
}

// ---------------- launch ----------------
extern "C" void kernel_launch(void* const* d_in, const int* in_sizes, int n_in,
                              void* d_out, int out_size, void* d_ws, size_t ws_size,
                              hipStream_t stream) {
  const float* x = (const float*)d_in[0];
  // d_in[1] = causal mask (implemented analytically)
  const float* w_attn = (const float*)d_in[2];
  const float* b_attn = (const float*)d_in[3];
  const float* w_proj = (const float*)d_in[4];
  const float* b_proj = (const float*)d_in[5];
  float* out = (float*)d_out;

  char* ws = (char*)d_ws;
  __bf16* xb    = (__bf16*)(ws + 0);          // 16 MB  [4096][2048] (reused as zb)
  __bf16* wqkv  = (__bf16*)(ws + 16777216);   // 24 MB  [6144][2048] (W^T)
  __bf16* wpro  = (__bf16*)(ws + 41943040);   //  8 MB  [2048][2048] (W^T)
  __bf16* qb    = (__bf16*)(ws + 50331648);   // 16 MB  [bh][s][d]
  __bf16* kb    = (__bf16*)(ws + 67108864);   // 16 MB  [bh][s][d]
  __bf16* vtb   = (__bf16*)(ws + 83886080);   // 16 MB  [bh][d][s]
  __bf16* zb    = xb;  // x fully consumed by QKV GEMM before attention writes z

  (void)hipFuncSetAttribute((const void*)k_qkv8p,
                            hipFuncAttributeMaxDynamicSharedMemorySize, 131072);
  (void)hipFuncSetAttribute((const void*)k_proj8p,
                            hipFuncAttributeMaxDynamicSharedMemorySize, 98304);
  (void)hipFuncSetAttribute((const void*)k_attn,
                            hipFuncAttributeMaxDynamicSharedMemorySize, 49152);

  // fused prep: 8192 cvt + 3072 w_attn-transpose + 1024 w_proj-transpose
  k_prep<<<12288, 256, 0, stream>>>(x, xb, w_attn, wqkv, w_proj, wpro);
  // QKV: M=4096 (32 x 128), N=6144 (16 x 384) -> 512 blocks = 2 exact rounds
  k_qkv8p<<<512, 512, 131072, stream>>>(xb, wqkv, b_attn, qb, kb, vtb);
  // attention: 512 blocks, 48 KB LDS -> 3 blocks/CU fit (all co-resident)
  k_attn<<<512, 256, 49152, stream>>>(qb, kb, vtb, zb);
  // out-proj: M=4096 (32 x 128), N=2048 (8 x 256) -> 256 blocks = 1/CU exact
  k_proj8p<<<256, 512, 98304, stream>>>(zb, wpro, b_proj, out);
}

// Round 21
// 224.355 us; speedup vs baseline: 1.2125x; 1.2125x over previous
//
#include <hip/hip_runtime.h>
#include <hip/hip_bf16.h>
#include <stdint.h>

typedef __attribute__((ext_vector_type(8))) __bf16 bf16x8;
typedef __attribute__((ext_vector_type(4))) __bf16 bf16x4;
typedef __attribute__((ext_vector_type(4))) float f32x4;

#define DEV __device__ __forceinline__

static constexpr int S = 2048, F = 2048, H = 16, D = 128;
static constexpr int KDIM = F;            // 2048
static constexpr float QSCALE = 0.08838834764831845f;  // 1/sqrt(128)

DEV void gll16(const void* g, void* l) {
  __builtin_amdgcn_global_load_lds(
      (const __attribute__((address_space(1))) void*)g,
      (__attribute__((address_space(3))) void*)l, 16, 0, 0);
}

DEV f32x4 mfma16(bf16x8 a, bf16x8 b, f32x4 c) {
  return __builtin_amdgcn_mfma_f32_16x16x32_bf16(a, b, c, 0, 0, 0);
}

extern __shared__ char smem[];

#define QBAR()  __builtin_amdgcn_s_barrier()
#define QLGKM() asm volatile("s_waitcnt lgkmcnt(0)" ::: "memory")
#define QSCB()  __builtin_amdgcn_sched_barrier(0)

// ---------------- fused prep: x->bf16 cvt + both weight transposes ----------------
__global__ void k_prep(const float* __restrict__ x, __bf16* __restrict__ xb,
                       const float* __restrict__ wa, __bf16* __restrict__ wat,
                       const float* __restrict__ wp, __bf16* __restrict__ wpt) {
  __shared__ float t[64][65];
  const int bid = blockIdx.x;
  if (bid < 8192) {
    int i = bid * 256 + threadIdx.x;
    float4 v = reinterpret_cast<const float4*>(x)[i];
    bf16x4 o = {(__bf16)v.x, (__bf16)v.y, (__bf16)v.z, (__bf16)v.w};
    reinterpret_cast<bf16x4*>(xb)[i] = o;
    return;
  }
  const float* in;
  __bf16* out;
  int rows, cols, c0, r0;
  if (bid < 11264) {
    int tb = bid - 8192;
    in = wa; out = wat; rows = 2048; cols = 6144;
    c0 = (tb % 96) * 64; r0 = (tb / 96) * 64;
  } else {
    int tb = bid - 11264;
    in = wp; out = wpt; rows = 2048; cols = 2048;
    c0 = (tb % 32) * 64; r0 = (tb / 32) * 64;
  }
  const int tx = threadIdx.x & 63, ty = threadIdx.x >> 6;
#pragma unroll
  for (int i = 0; i < 64; i += 4)
    t[ty + i][tx] = in[(size_t)(r0 + ty + i) * cols + c0 + tx];
  __syncthreads();
#pragma unroll
  for (int i = 0; i < 64; i += 4)
    out[(size_t)(c0 + ty + i) * rows + r0 + tx] = (__bf16)t[tx][ty + i];
}

// ================= QKV: 8-phase barrier-dense GEMM, 128x384 tile, BK=64 ==========
// (r17 — measured 105.3 us, MfmaUtil 42%, no spill, tail-free 512 blocks)
__global__ __launch_bounds__(512, 1) void k_qkv8p(
    const __bf16* __restrict__ A, const __bf16* __restrict__ Bt,
    const float* __restrict__ bias,
    __bf16* __restrict__ qo, __bf16* __restrict__ ko, __bf16* __restrict__ vo) {
  constexpr int NT = 32;
  const int tid = threadIdx.x;
  const int lane = tid & 63, wid = tid >> 6;
  const int wm = wid >> 2, wn = wid & 3;
  const int ln = lane & 15, lm = lane >> 4;

  const int lin = (blockIdx.x & 7) * 64 + (blockIdx.x >> 3);
  const int by = lin >> 4, bx = lin & 15;
  const int mBase = by * 128, nBase = bx * 384;

  const int r0 = tid >> 3, cc = tid & 7;
  const int src0 = r0 * KDIM + ((cc ^ (r0 & 7)) << 3);
  const __bf16* Ab = A + (size_t)mBase * KDIM + src0;
  const __bf16* Bb = Bt + (size_t)nBase * KDIM + src0;
  const int sDst = wid * 1024;

  auto stA2 = [&](int t) {
    char* d = smem + (t & 1) * 65536 + sDst;
    const __bf16* s = Ab + t * 64;
    gll16(s, d);
    gll16(s + (size_t)64 * KDIM, d + 8192);
  };
  auto stB2 = [&](int t, int j) {
    char* d = smem + (t & 1) * 65536 + 16384 + j * 8192 + sDst;
    const __bf16* s = Bb + (size_t)j * 64 * KDIM + t * 64;
    gll16(s, d);
    gll16(s + (size_t)64 * KDIM, d + 8192);
  };

  int rA[2], rB[2];
#pragma unroll
  for (int ks = 0; ks < 2; ++ks) {
    const int slot = (ks * 4 + lm) ^ (ln & 7);
    rA[ks] = (wm * 64 + ln) * 128 + slot * 16;
    rB[ks] = 16384 + (wn * 96 + ln) * 128 + slot * 16;
  }
  auto rdA = [&](bf16x8 (&a)[4], const char* cb, int ks) {
#pragma unroll
    for (int mi = 0; mi < 4; ++mi)
      a[mi] = *reinterpret_cast<const bf16x8*>(cb + rA[ks] + mi * 2048);
  };
  auto rdBh = [&](bf16x8 (&b)[3], const char* cb, int ks, int h) {
#pragma unroll
    for (int k = 0; k < 3; ++k)
      b[k] = *reinterpret_cast<const bf16x8*>(cb + rB[ks] + (h * 3 + k) * 2048);
  };

  f32x4 acc[4][6] = {};
  auto mm = [&](const bf16x8 (&a)[4], const bf16x8 (&b)[3], int h) {
#pragma unroll
    for (int k = 0; k < 3; ++k)
#pragma unroll
      for (int mi = 0; mi < 4; ++mi)
        acc[mi][h * 3 + k] = mfma16(a[mi], b[k], acc[mi][h * 3 + k]);
  };

  stA2(0); stB2(0, 0); stB2(0, 2); stB2(0, 4); stA2(1);
  asm volatile("s_waitcnt vmcnt(2)" ::: "memory");
  QBAR(); QSCB();

  for (int i = 0; i < 16; ++i) {
    const char* L = smem;
    const char* R = smem + 65536;
    const int tR = 2 * i + 1, tN = 2 * i + 2, tN1 = 2 * i + 3;
    const bool last = (i == 15);
    bf16x8 a[4], b[3];

    rdA(a, L, 0); rdBh(b, L, 0, 0);
    stB2(tR, 0);
    QBAR(); QLGKM(); QSCB();
    __builtin_amdgcn_s_setprio(1); mm(a, b, 0); __builtin_amdgcn_s_setprio(0);
    QBAR(); QSCB();

    rdBh(b, L, 0, 1);
    stB2(tR, 2);
    QBAR(); QLGKM(); QSCB();
    __builtin_amdgcn_s_setprio(1); mm(a, b, 1); __builtin_amdgcn_s_setprio(0);
    QBAR(); QSCB();

    rdA(a, L, 1); rdBh(b, L, 1, 1);
    stB2(tR, 4);
    QBAR(); QLGKM(); QSCB();
    __builtin_amdgcn_s_setprio(1); mm(a, b, 1); __builtin_amdgcn_s_setprio(0);
    QBAR(); QSCB();

    rdBh(b, L, 1, 0);
    if (!last) stA2(tN);
    QBAR(); QLGKM(); QSCB();
    __builtin_amdgcn_s_setprio(1); mm(a, b, 0); __builtin_amdgcn_s_setprio(0);
    if (last) asm volatile("s_waitcnt vmcnt(0)" ::: "memory");
    else      asm volatile("s_waitcnt vmcnt(2)" ::: "memory");
    QBAR(); QSCB();

    rdA(a, R, 0); rdBh(b, R, 0, 0);
    if (!last) stB2(tN, 0);
    QBAR(); QLGKM(); QSCB();
    __builtin_amdgcn_s_setprio(1); mm(a, b, 0); __builtin_amdgcn_s_setprio(0);
    QBAR(); QSCB();

    rdBh(b, R, 0, 1);
    if (!last) stB2(tN, 2);
    QBAR(); QLGKM(); QSCB();
    __builtin_amdgcn_s_setprio(1); mm(a, b, 1); __builtin_amdgcn_s_setprio(0);
    QBAR(); QSCB();

    rdA(a, R, 1); rdBh(b, R, 1, 1);
    if (!last) stB2(tN, 4);
    QBAR(); QLGKM(); QSCB();
    __builtin_amdgcn_s_setprio(1); mm(a, b, 1); __builtin_amdgcn_s_setprio(0);
    QBAR(); QSCB();

    rdBh(b, R, 1, 0);
    if (tN1 < NT) stA2(tN1);
    QBAR(); QLGKM(); QSCB();
    __builtin_amdgcn_s_setprio(1); mm(a, b, 0); __builtin_amdgcn_s_setprio(0);
    if (!last) {
      asm volatile("s_waitcnt vmcnt(2)" ::: "memory");
      QBAR(); QSCB();
    }
  }

#pragma unroll
  for (int mi = 0; mi < 4; ++mi) {
    const int grow = mBase + wm * 64 + mi * 16 + lm * 4;
    const int b = grow >> 11, s0 = grow & 2047;
#pragma unroll
    for (int ni = 0; ni < 6; ++ni) {
      const int gcol = nBase + wn * 96 + ni * 16 + ln;
      const float bv = bias[gcol];
      const int sec = gcol >> 11;
      const int h = (gcol >> 7) & 15, d = gcol & 127;
      const int bh = b * H + h;
      if (sec == 0) {
#pragma unroll
        for (int r = 0; r < 4; ++r)
          qo[((size_t)bh * S + s0 + r) * D + d] = (__bf16)((acc[mi][ni][r] + bv) * QSCALE);
      } else if (sec == 1) {
#pragma unroll
        for (int r = 0; r < 4; ++r)
          ko[((size_t)bh * S + s0 + r) * D + d] = (__bf16)(acc[mi][ni][r] + bv);
      } else {
        bf16x4 pv = {(__bf16)(acc[mi][ni][0] + bv), (__bf16)(acc[mi][ni][1] + bv),
                     (__bf16)(acc[mi][ni][2] + bv), (__bf16)(acc[mi][ni][3] + bv)};
        *reinterpret_cast<bf16x4*>(vo + ((size_t)bh * D + d) * S + s0) = pv;  // V^T
      }
    }
  }
}

// ================= out-proj: 8-phase barrier-dense GEMM, 128x256 tile =============
// (r18 — best proj)
__global__ __launch_bounds__(512, 1) void k_proj8p(
    const __bf16* __restrict__ A, const __bf16* __restrict__ Bt,
    const float* __restrict__ bias, float* __restrict__ fo) {
  constexpr int NT = 32;
  const int tid = threadIdx.x;
  const int lane = tid & 63, wid = tid >> 6;
  const int wm = wid >> 2, wn = wid & 3;
  const int ln = lane & 15, lm = lane >> 4;

  const int lin = (blockIdx.x & 7) * 32 + (blockIdx.x >> 3);
  const int by = lin >> 3, bx = lin & 7;
  const int mBase = by * 128, nBase = bx * 256;

  const int r0 = tid >> 3, cc = tid & 7;
  const int src0 = r0 * KDIM + ((cc ^ (r0 & 7)) << 3);
  const __bf16* Ab = A + (size_t)mBase * KDIM + src0;
  const __bf16* Bb = Bt + (size_t)nBase * KDIM + src0;
  const int sDst = wid * 1024;

  auto stA2 = [&](int t) {
    char* d = smem + (t & 1) * 49152 + sDst;
    const __bf16* s = Ab + t * 64;
    gll16(s, d);
    gll16(s + (size_t)64 * KDIM, d + 8192);
  };
  auto stB2 = [&](int t, int j) {
    char* d = smem + (t & 1) * 49152 + 16384 + j * 8192 + sDst;
    const __bf16* s = Bb + (size_t)j * 64 * KDIM + t * 64;
    gll16(s, d);
    gll16(s + (size_t)64 * KDIM, d + 8192);
  };

  int rA[2], rB[2];
#pragma unroll
  for (int ks = 0; ks < 2; ++ks) {
    const int slot = (ks * 4 + lm) ^ (ln & 7);
    rA[ks] = (wm * 64 + ln) * 128 + slot * 16;
    rB[ks] = 16384 + (wn * 64 + ln) * 128 + slot * 16;
  }
  auto rdA = [&](bf16x8 (&a)[4], const char* cb, int ks) {
#pragma unroll
    for (int mi = 0; mi < 4; ++mi)
      a[mi] = *reinterpret_cast<const bf16x8*>(cb + rA[ks] + mi * 2048);
  };
  auto rdBh = [&](bf16x8 (&b)[2], const char* cb, int ks, int h) {
#pragma unroll
    for (int k = 0; k < 2; ++k)
      b[k] = *reinterpret_cast<const bf16x8*>(cb + rB[ks] + (h * 2 + k) * 2048);
  };

  f32x4 acc[4][4] = {};
  auto mm = [&](const bf16x8 (&a)[4], const bf16x8 (&b)[2], int h) {
#pragma unroll
    for (int k = 0; k < 2; ++k)
#pragma unroll
      for (int mi = 0; mi < 4; ++mi)
        acc[mi][h * 2 + k] = mfma16(a[mi], b[k], acc[mi][h * 2 + k]);
  };

  stA2(0); stB2(0, 0); stB2(0, 2); stA2(1);
  asm volatile("s_waitcnt vmcnt(2)" ::: "memory");
  QBAR(); QSCB();

  for (int i = 0; i < 16; ++i) {
    const char* L = smem;
    const char* R = smem + 49152;
    const int tR = 2 * i + 1, tN = 2 * i + 2, tN1 = 2 * i + 3;
    const bool last = (i == 15);
    bf16x8 a[4], b[2];

    rdA(a, L, 0); rdBh(b, L, 0, 0);
    stB2(tR, 0);
    QBAR(); QLGKM(); QSCB();
    __builtin_amdgcn_s_setprio(1); mm(a, b, 0); __builtin_amdgcn_s_setprio(0);
    QBAR(); QSCB();

    rdBh(b, L, 0, 1);
    stB2(tR, 2);
    QBAR(); QLGKM(); QSCB();
    __builtin_amdgcn_s_setprio(1); mm(a, b, 1); __builtin_amdgcn_s_setprio(0);
    QBAR(); QSCB();

    rdA(a, L, 1); rdBh(b, L, 1, 1);
    if (!last) stA2(tN);
    QBAR(); QLGKM(); QSCB();
    __builtin_amdgcn_s_setprio(1); mm(a, b, 1); __builtin_amdgcn_s_setprio(0);
    QBAR(); QSCB();

    rdBh(b, L, 1, 0);
    QBAR(); QLGKM(); QSCB();
    __builtin_amdgcn_s_setprio(1); mm(a, b, 0); __builtin_amdgcn_s_setprio(0);
    if (last) asm volatile("s_waitcnt vmcnt(0)" ::: "memory");
    else      asm volatile("s_waitcnt vmcnt(2)" ::: "memory");
    QBAR(); QSCB();

    rdA(a, R, 0); rdBh(b, R, 0, 0);
    if (!last) stB2(tN, 0);
    QBAR(); QLGKM(); QSCB();
    __builtin_amdgcn_s_setprio(1); mm(a, b, 0); __builtin_amdgcn_s_setprio(0);
    QBAR(); QSCB();

    rdBh(b, R, 0, 1);
    if (!last) stB2(tN, 2);
    QBAR(); QLGKM(); QSCB();
    __builtin_amdgcn_s_setprio(1); mm(a, b, 1); __builtin_amdgcn_s_setprio(0);
    QBAR(); QSCB();

    rdA(a, R, 1); rdBh(b, R, 1, 1);
    if (tN1 < NT) stA2(tN1);
    QBAR(); QLGKM(); QSCB();
    __builtin_amdgcn_s_setprio(1); mm(a, b, 1); __builtin_amdgcn_s_setprio(0);
    QBAR(); QSCB();

    rdBh(b, R, 1, 0);
    QBAR(); QLGKM(); QSCB();
    __builtin_amdgcn_s_setprio(1); mm(a, b, 0); __builtin_amdgcn_s_setprio(0);
    if (!last) {
      asm volatile("s_waitcnt vmcnt(2)" ::: "memory");
      QBAR(); QSCB();
    }
  }

#pragma unroll
  for (int mi = 0; mi < 4; ++mi) {
    const int grow = mBase + wm * 64 + mi * 16 + lm * 4;
#pragma unroll
    for (int ni = 0; ni < 4; ++ni) {
      const int gcol = nBase + wn * 64 + ni * 16 + ln;
      const float bv = bias[gcol];
#pragma unroll
      for (int r = 0; r < 4; ++r)
        fo[(size_t)(grow + r) * F + gcol] = acc[mi][ni][r] + bv;
    }
  }
}

// ---------------- flash attention: SWAPPED-OPERAND (r19 — best measured) ----------
// S^T = mfma(A=K, B=Q): lane owns one q-row (col=ln). K+V staged via DMA (the
// staging IS the coalescer: r20's direct-global V read was stride-4096 ->
// 3.2M bank conflicts + MfmaUtil 11%). P round-trip: 8 b64 writes; PV =
// mfma(A=V^T, B=P^T) -> O^T; packed bf16x4 epilogue stores.
__global__ __launch_bounds__(256, 2) void k_attn(
    const __bf16* __restrict__ qb, const __bf16* __restrict__ kb,
    const __bf16* __restrict__ vtb, __bf16* __restrict__ zb) {
  const int lane = threadIdx.x & 63, w = threadIdx.x >> 6;
  const int lm = lane >> 4, ln = lane & 15;
  const int blk = blockIdx.x;
  const int u = blk & 255, v = blk >> 8;
  const int qt = v ? (u >> 4) : 15 - (u >> 4);
  const int bh = ((u & 15) << 1) | v;
  const int qw = qt * 128 + w * 32;

  const __bf16* qp = qb + (size_t)bh * S * D;
  const __bf16* kp = kb + (size_t)bh * S * D;
  const __bf16* vp = vtb + (size_t)bh * D * S;
  char* pw = smem + 65536 + w * 4096;

  int ksrc[4], kdst[4], vsrc[4], vdst[4];
#pragma unroll
  for (int j = 0; j < 4; ++j) {
    int c = (w * 4 + j) * 64 + lane;
    int kr = c >> 4, kps = (c & 15) ^ (kr & 7);
    ksrc[j] = kr * D + kps * 8;
    kdst[j] = (w * 4 + j) * 1024;
    int vr = c >> 3, vps = (c & 7) ^ (vr & 7);
    vsrc[j] = vr * S + vps * 8;
    vdst[j] = 16384 + (w * 4 + j) * 1024;
  }
  auto stage = [&](int kt) {
    char* buf = smem + (kt & 1) * 32768;
    const int kv = kt * 64;
#pragma unroll
    for (int j = 0; j < 4; ++j) gll16(kp + (size_t)kv * D + ksrc[j], buf + kdst[j]);
#pragma unroll
    for (int j = 0; j < 4; ++j) gll16(vp + kv + vsrc[j], buf + vdst[j]);
  };

  // Q frags (B-operand): col=q=qw+nj*16+ln, k-elems d=kf*32+lm*8..
  bf16x8 qf[2][4];
#pragma unroll
  for (int nj = 0; nj < 2; ++nj)
#pragma unroll
    for (int kf = 0; kf < 4; ++kf)
      qf[nj][kf] = *reinterpret_cast<const bf16x8*>(qp + (qw + nj * 16 + ln) * D + kf * 32 + lm * 8);

  f32x4 Oa[8][2] = {};            // O^T: [d-frag][q-frag]
  float mrow[2], lrow[2];         // per q-frag (q = nj*16+ln)
#pragma unroll
  for (int nj = 0; nj < 2; ++nj) { mrow[nj] = -3.0e38f; lrow[nj] = 0.0f; }

  const int ktEnd = 2 * qt + 1;

  stage(0);
  stage(1);
  asm volatile("s_waitcnt vmcnt(8)" ::: "memory");
  QBAR(); QSCB();

  for (int kt = 0; kt <= ktEnd; ++kt) {
    const int kv0 = kt * 64;
    const int cur = kt & 1;
    const char* Kb = smem + cur * 32768;
    const char* Vb = Kb + 16384;

    if (kv0 <= qw + 31) {
      const bool diag = (kv0 + 63 > qw);

      // S^T = K Q^T : M=64(kv) N=32(q) K=128(d); sacc[mi=kv-frag][nj=q-frag]
      f32x4 sacc[4][2] = {};
#pragma unroll
      for (int kf = 0; kf < 4; ++kf) {
        bf16x8 kfr[4];  // A-operand: row=kv=mi*16+ln, k=d=kf*32+lm*8..
#pragma unroll
        for (int mi = 0; mi < 4; ++mi) {
          int row = mi * 16 + ln;
          int ch = (kf * 4 + lm) ^ (row & 7);
          kfr[mi] = *reinterpret_cast<const bf16x8*>(Kb + row * 256 + ch * 16);
        }
        __builtin_amdgcn_s_setprio(1);
#pragma unroll
        for (int mi = 0; mi < 4; ++mi)
#pragma unroll
          for (int nj = 0; nj < 2; ++nj)
            sacc[mi][nj] = mfma16(kfr[mi], qf[nj][kf], sacc[mi][nj]);
        __builtin_amdgcn_s_setprio(0);
      }

      if (diag) {
#pragma unroll
        for (int nj = 0; nj < 2; ++nj) {
          int q = qw + nj * 16 + ln;
#pragma unroll
          for (int mi = 0; mi < 4; ++mi) {
            int kvb = kv0 + mi * 16 + lm * 4;
#pragma unroll
            for (int r = 0; r < 4; ++r)
              if (kvb + r > q) sacc[mi][nj][r] = -1e30f;
          }
        }
      }

      // softmax: lane owns 16 kv of its q-row; fast-path lane-partial trigger
      float lmax[2];
      bool big = false;
#pragma unroll
      for (int nj = 0; nj < 2; ++nj) {
        float m4 = -3.0e38f;
#pragma unroll
        for (int mi = 0; mi < 4; ++mi)
#pragma unroll
          for (int r = 0; r < 4; ++r) m4 = fmaxf(m4, sacc[mi][nj][r]);
        lmax[nj] = m4;
        big = big || (m4 > mrow[nj] + 8.0f);
      }
      if (__any((int)big)) {  // rare: 2-shuffle row reduce + rescale
#pragma unroll
        for (int nj = 0; nj < 2; ++nj) {
          float mx = lmax[nj];
          mx = fmaxf(mx, __shfl_xor(mx, 16, 64));
          mx = fmaxf(mx, __shfl_xor(mx, 32, 64));
          float mnew = fmaxf(mrow[nj], mx);
          float corr = __expf(mrow[nj] - mnew);
          mrow[nj] = mnew;
          lrow[nj] *= corr;
#pragma unroll
          for (int ni = 0; ni < 8; ++ni)
#pragma unroll
            for (int r = 0; r < 4; ++r) Oa[ni][nj][r] *= corr;
        }
      }
#pragma unroll
      for (int nj = 0; nj < 2; ++nj) {
        float rs = 0.0f;
#pragma unroll
        for (int mi = 0; mi < 4; ++mi)
#pragma unroll
          for (int r = 0; r < 4; ++r) {
            float p = __expf(sacc[mi][nj][r] - mrow[nj]);  // bounded by e^8
            sacc[mi][nj][r] = p;
            rs += p;
          }
        lrow[nj] += rs;  // lane-partial over 16 kv; reduced at the end
      }

      // P^T -> per-wave LDS: 8 b64 writes (row q=nj*16+ln, kv-quad at mi*32+lm*8)
#pragma unroll
      for (int nj = 0; nj < 2; ++nj) {
        int row = nj * 16 + ln;
        int rb = row * 128;
        int swz = (row & 7) << 4;
#pragma unroll
        for (int mi = 0; mi < 4; ++mi) {
          bf16x4 pq = {(__bf16)sacc[mi][nj][0], (__bf16)sacc[mi][nj][1],
                       (__bf16)sacc[mi][nj][2], (__bf16)sacc[mi][nj][3]};
          *reinterpret_cast<bf16x4*>(pw + rb + ((mi * 32 + lm * 8) ^ swz)) = pq;
        }
      }

      QLGKM(); QSCB();

      // O^T += V^T P^T : M=128(d) N=32(q) K=64(kv)
#pragma unroll
      for (int kf = 0; kf < 2; ++kf) {
        bf16x8 pfr[2], vfr[8];
#pragma unroll
        for (int nj = 0; nj < 2; ++nj) {  // B: col=q=nj*16+ln, k=kv=kf*32+lm*8..
          int row = nj * 16 + ln;
          pfr[nj] = *reinterpret_cast<const bf16x8*>(
              pw + row * 128 + ((kf * 64 + lm * 16) ^ ((row & 7) << 4)));
        }
#pragma unroll
        for (int ni = 0; ni < 8; ++ni) {  // A: row=d=ni*16+ln, k=kv
          int row = ni * 16 + ln;
          int ch = (kf * 4 + lm) ^ (row & 7);
          vfr[ni] = *reinterpret_cast<const bf16x8*>(Vb + row * 128 + ch * 16);
        }
        __builtin_amdgcn_s_setprio(1);
#pragma unroll
        for (int ni = 0; ni < 8; ++ni)
#pragma unroll
          for (int nj = 0; nj < 2; ++nj)
            Oa[ni][nj] = mfma16(vfr[ni], pfr[nj], Oa[ni][nj]);
        __builtin_amdgcn_s_setprio(0);
      }
    }

    // ---- tile boundary: counted waits, never drain mid-loop ----
    asm volatile("s_waitcnt lgkmcnt(0)" ::: "memory");
    QBAR(); QSCB();
    if (kt + 2 <= ktEnd) stage(kt + 2);
    if (kt + 1 <= ktEnd) {
      if (kt + 2 <= ktEnd)
        asm volatile("s_waitcnt vmcnt(8)" ::: "memory");
      else
        asm volatile("s_waitcnt vmcnt(0)" ::: "memory");
      QBAR(); QSCB();
    }
  }

  // finish: 2-shuffle row-sum reduce, normalize, packed 8B stores of d-quads
#pragma unroll
  for (int nj = 0; nj < 2; ++nj) {
    float ls = lrow[nj];
    ls += __shfl_xor(ls, 16, 64);
    ls += __shfl_xor(ls, 32, 64);
    lrow[nj] = 1.0f / ls;
  }
  const int b = bh >> 4, h = bh & 15;
#pragma unroll
  for (int nj = 0; nj < 2; ++nj) {
    const int qrow = qw + nj * 16 + ln;
    __bf16* zrow = zb + (size_t)(b * S + qrow) * F + h * D + lm * 4;
#pragma unroll
    for (int ni = 0; ni < 8; ++ni) {
      bf16x4 oq = {(__bf16)(Oa[ni][nj][0] * lrow[nj]), (__bf16)(Oa[ni][nj][1] * lrow[nj]),
                   (__bf16)(Oa[ni][nj][2] * lrow[nj]), (__bf16)(Oa[ni][nj][3] * lrow[nj])};
      *reinterpret_cast<bf16x4*>(zrow + ni * 16) = oq;
    }
  }
}

// ---------------- launch ----------------
extern "C" void kernel_launch(void* const* d_in, const int* in_sizes, int n_in,
                              void* d_out, int out_size, void* d_ws, size_t ws_size,
                              hipStream_t stream) {
  const float* x = (const float*)d_in[0];
  // d_in[1] = causal mask (implemented analytically)
  const float* w_attn = (const float*)d_in[2];
  const float* b_attn = (const float*)d_in[3];
  const float* w_proj = (const float*)d_in[4];
  const float* b_proj = (const float*)d_in[5];
  float* out = (float*)d_out;

  char* ws = (char*)d_ws;
  __bf16* xb    = (__bf16*)(ws + 0);          // 16 MB  [4096][2048] (reused as zb)
  __bf16* wqkv  = (__bf16*)(ws + 16777216);   // 24 MB  [6144][2048] (W^T)
  __bf16* wpro  = (__bf16*)(ws + 41943040);   //  8 MB  [2048][2048] (W^T)
  __bf16* qb    = (__bf16*)(ws + 50331648);   // 16 MB  [bh][s][d]
  __bf16* kb    = (__bf16*)(ws + 67108864);   // 16 MB  [bh][s][d]
  __bf16* vtb   = (__bf16*)(ws + 83886080);   // 16 MB  [bh][d][s]
  __bf16* zb    = xb;  // x fully consumed by QKV GEMM before attention writes z

  (void)hipFuncSetAttribute((const void*)k_qkv8p,
                            hipFuncAttributeMaxDynamicSharedMemorySize, 131072);
  (void)hipFuncSetAttribute((const void*)k_proj8p,
                            hipFuncAttributeMaxDynamicSharedMemorySize, 98304);
  (void)hipFuncSetAttribute((const void*)k_attn,
                            hipFuncAttributeMaxDynamicSharedMemorySize, 81920);

  // fused prep: 8192 cvt + 3072 w_attn-transpose + 1024 w_proj-transpose
  k_prep<<<12288, 256, 0, stream>>>(x, xb, w_attn, wqkv, w_proj, wpro);
  // QKV: M=4096 (32 x 128), N=6144 (16 x 384) -> 512 blocks = 2 exact rounds
  k_qkv8p<<<512, 512, 131072, stream>>>(xb, wqkv, b_attn, qb, kb, vtb);
  // attention: 512 blocks (complementary-qt balance + XCD affinity inside)
  k_attn<<<512, 256, 81920, stream>>>(qb, kb, vtb, zb);
  // out-proj: M=4096 (32 x 128), N=2048 (8 x 256) -> 256 blocks = 1/CU exact
  k_proj8p<<<256, 512, 98304, stream>>>(zb, wpro, b_proj, out);
}